// Round 9
// baseline (10882.406 us; speedup 1.0000x reference)
//
#include <hip/hip_runtime.h>

typedef _Float16 half8 __attribute__((ext_vector_type(8)));
typedef float floatx4 __attribute__((ext_vector_type(4)));

#define S_LEN 512
#define NB 64
#define NI 256
#define NR 2048
#define LEAK 0.9f

#define NBLK 256
#define TPB 512
#define NBNR ((size_t)NB * NR)

// ---- workspace offsets ----
#define OFF_BAR ((size_t)0)
#define OFF_H0  ((size_t)4096)                 /* 2-parity fragment-order h exch, layer0 (=y0) */
#define OFF_H1  (OFF_H0 + 2 * NBNR * 2)        /* layer1 */
#define OFF_XE  (OFF_H1 + 2 * NBNR * 2)        /* x in fragment order, per t */

__device__ __forceinline__ half8 cvt8(const float* s) {
    float4 p = *(const float4*)s, q = *(const float4*)(s + 4);
    half8 v;
    v[0] = (_Float16)p.x; v[1] = (_Float16)p.y; v[2] = (_Float16)p.z; v[3] = (_Float16)p.w;
    v[4] = (_Float16)q.x; v[5] = (_Float16)q.y; v[6] = (_Float16)q.z; v[7] = (_Float16)q.w;
    return v;
}

// x fp32 -> fp16 in fragment order: per t, 32 units of 1KB; unit u=(bt*8+c),
// element (l*8+e) <-> (batch=bt*16+(l&15), i=c*32+(l>>4)*8+e)
__global__ void xprep_kernel(const float* __restrict__ x, _Float16* __restrict__ xe) {
    const int t = blockIdx.x;
    #pragma unroll
    for (int it = 0; it < 4; ++it) {
        const int u = it * 8 + (threadIdx.x >> 6);
        const int l = threadIdx.x & 63;
        const int b = (u >> 3) * 16 + (l & 15);
        const int i0 = (u & 7) * 32 + (l >> 4) * 8;
        half8 v = cvt8(x + ((size_t)t * NB + b) * NI + i0);
        *(half8*)(xe + (size_t)t * NB * NI + (size_t)u * 512 + (size_t)l * 8) = v;
    }
}

// write-through 2B publish (agent-scope relaxed: reaches LLC, never dirty in L2)
__device__ __forceinline__ void stH(_Float16* p, _Float16 v) {
    unsigned short b;
    __builtin_memcpy(&b, &v, 2);
    __hip_atomic_store((unsigned short*)p, b, __ATOMIC_RELAXED, __HIP_MEMORY_SCOPE_AGENT);
}

// two-level grid barrier; publishes are write-through so NO release fence.
// Acquire fence after release invalidates L1/L2 (global data only; LDS untouched).
__device__ __forceinline__ void gbar(unsigned* bar) {
    __syncthreads();                       // drains vmcnt: all publishes at LLC
    if (threadIdx.x == 0) {
        unsigned* cnt  = bar + (blockIdx.x & 7) * 32;
        unsigned* root = bar + 256;
        unsigned* gen  = bar + 272;
        unsigned g = __hip_atomic_load(gen, __ATOMIC_RELAXED, __HIP_MEMORY_SCOPE_AGENT);
        bool last = false;
        if (__hip_atomic_fetch_add(cnt, 1u, __ATOMIC_RELAXED, __HIP_MEMORY_SCOPE_AGENT) == (NBLK / 8 - 1)) {
            __hip_atomic_store(cnt, 0u, __ATOMIC_RELAXED, __HIP_MEMORY_SCOPE_AGENT);
            if (__hip_atomic_fetch_add(root, 1u, __ATOMIC_ACQ_REL, __HIP_MEMORY_SCOPE_AGENT) == 7u) {
                __hip_atomic_store(root, 0u, __ATOMIC_RELAXED, __HIP_MEMORY_SCOPE_AGENT);
                __hip_atomic_store(gen, g + 1u, __ATOMIC_RELEASE, __HIP_MEMORY_SCOPE_AGENT);
                last = true;
            }
        }
        if (!last)
            while (__hip_atomic_load(gen, __ATOMIC_RELAXED, __HIP_MEMORY_SCOPE_AGENT) == g)
                __builtin_amdgcn_s_sleep(2);
    }
    __syncthreads();
    __builtin_amdgcn_fence(__ATOMIC_ACQUIRE, "agent");
}

// One layer, persistent. Block = 32 feats x 32 batches. 8 waves = K-slices.
// Weights: fg0 (16 feats) in VGPRs, fg1 (16 feats) in LDS fragment-order units
// (1KB per (wave,chunk), lane*16 within) -> structurally resident, conflict-free.
template <int CH, int KU, int ROLE>
__device__ __forceinline__ void esn_layer_run(
    const float* __restrict__ bias_v,
    const float* Whh, const float* Win,
    const char* __restrict__ xe,       // ROLE 0: x exchange
    char* hp,                          // own h exchange ping-pong
    const char* h0p,                   // ROLE 1: producer (y0) exchange
    float* __restrict__ out,
    unsigned* __restrict__ bar,
    char* wlds, float* rsc, int r0, int bhalf)
{
    const int tid = threadIdx.x;
    const int l = tid & 63, w = tid >> 6, l15 = l & 15, g = l >> 4;

    // ---- fg0 weights (16 feats) into registers ----
    half8 bwA[CH];
    #pragma unroll
    for (int j = 0; j < CH; ++j) {
        const float* s0;
        if (j < 8)          s0 = Whh + (size_t)(r0 + l15) * NR + (w * 8 + j) * 32 + g * 8;
        else if (ROLE == 0) s0 = Win + (size_t)(r0 + l15) * KU + w * 32 + g * 8;
        else                s0 = Win + (size_t)(r0 + l15) * KU + (w * 8 + j - 8) * 32 + g * 8;
        bwA[j] = cvt8(s0);
        asm volatile("" : "+v"(bwA[j]));
    }
    // ---- fg1 weights (16 feats) into LDS, fragment order ----
    #pragma unroll
    for (int j = 0; j < CH; ++j) {
        const float* s1;
        if (j < 8)          s1 = Whh + (size_t)(r0 + 16 + l15) * NR + (w * 8 + j) * 32 + g * 8;
        else if (ROLE == 0) s1 = Win + (size_t)(r0 + 16 + l15) * KU + w * 32 + g * 8;
        else                s1 = Win + (size_t)(r0 + 16 + l15) * KU + (w * 8 + j - 8) * 32 + g * 8;
        *(half8*)(wlds + ((size_t)(w * CH + j) << 10) + (size_t)l * 16) = cvt8(s1);
    }
    __syncthreads();

    // epilogue ownership: waves 0..3 own tile (fg_o = w&1, bt_o = (w>>1)&1)
    const int fg_o = w & 1, bt_o = (w >> 1) & 1;
    const bool owner = (w < 4);
    const int ncol = r0 + fg_o * 16 + l15;
    const float bias = owner ? bias_v[ncol] : 0.f;
    const int cu = ncol >> 5, gg = (ncol >> 3) & 3, ee = ncol & 7;
    float hs[4] = {0.f, 0.f, 0.f, 0.f};
    float* hn_base = out + (size_t)S_LEN * NBNR + (size_t)ROLE * NBNR;

    for (int s = 0; s < S_LEN + 1; ++s) {
        const int t = (ROLE == 0) ? s : s - 1;
        const bool active = (ROLE == 0) ? (s < S_LEN) : (s >= 1);
        if (active) {
            const char* hu = hp + (size_t)(t & 1) * (NBNR * 2);
            const char* uu = (ROLE == 0) ? xe + (size_t)t * NB * NI * 2
                                         : h0p + (size_t)((t + 1) & 1) * (NBNR * 2);
            const int bt_g0 = bhalf * 2, bt_g1 = bhalf * 2 + 1;

            floatx4 c00 = {0,0,0,0}, c01 = {0,0,0,0}, c10 = {0,0,0,0}, c11 = {0,0,0,0};

            #pragma unroll
            for (int hv = 0; hv < (CH + 7) / 8; ++hv) {
                const int jn = (hv == 0) ? ((CH < 8) ? CH : 8) : (CH - 8);
                half8 a0[8], a1[8], wb[8];
                #pragma unroll
                for (int jj = 0; jj < 8; ++jj) {
                    if (jj >= jn) break;
                    const int j = hv * 8 + jj;
                    const char* src; size_t u0, u1;
                    if (j < 8)          { src = hu; u0 = (size_t)(bt_g0 * 64 + w * 8 + j);  u1 = (size_t)(bt_g1 * 64 + w * 8 + j); }
                    else if (ROLE == 0) { src = uu; u0 = (size_t)(bt_g0 * 8 + w);           u1 = (size_t)(bt_g1 * 8 + w); }
                    else                { src = uu; u0 = (size_t)(bt_g0 * 64 + w * 8 + j - 8); u1 = (size_t)(bt_g1 * 64 + w * 8 + j - 8); }
                    a0[jj] = *(const half8*)(src + u0 * 1024 + (size_t)l * 16);
                    a1[jj] = *(const half8*)(src + u1 * 1024 + (size_t)l * 16);
                }
                #pragma unroll
                for (int jj = 0; jj < 8; ++jj) {
                    if (jj >= jn) break;
                    const int j = hv * 8 + jj;
                    wb[jj] = *(const half8*)(wlds + ((size_t)(w * CH + j) << 10) + (size_t)l * 16);
                }
                #pragma unroll
                for (int jj = 0; jj < 8; ++jj) {
                    if (jj >= jn) break;
                    const int j = hv * 8 + jj;
                    c00 = __builtin_amdgcn_mfma_f32_16x16x32_f16(a0[jj], bwA[j], c00, 0, 0, 0);
                    c01 = __builtin_amdgcn_mfma_f32_16x16x32_f16(a1[jj], bwA[j], c01, 0, 0, 0);
                    c10 = __builtin_amdgcn_mfma_f32_16x16x32_f16(a0[jj], wb[jj], c10, 0, 0, 0);
                    c11 = __builtin_amdgcn_mfma_f32_16x16x32_f16(a1[jj], wb[jj], c11, 0, 0, 0);
                }
            }

            // two-phase cross-wave K reduction (16 KB LDS)
            floatx4 r = {0.f, 0.f, 0.f, 0.f};
            // phase A: fg=0 tiles
            *(floatx4*)(rsc + (size_t)((w * 2 + 0) * 64 + l) * 4) = c00;
            *(floatx4*)(rsc + (size_t)((w * 2 + 1) * 64 + l) * 4) = c01;
            __syncthreads();
            if (owner && (w & 1) == 0) {
                #pragma unroll
                for (int v = 0; v < 8; ++v)
                    r += *(const floatx4*)(rsc + (size_t)((v * 2 + bt_o) * 64 + l) * 4);
            }
            __syncthreads();
            // phase B: fg=1 tiles
            *(floatx4*)(rsc + (size_t)((w * 2 + 0) * 64 + l) * 4) = c10;
            *(floatx4*)(rsc + (size_t)((w * 2 + 1) * 64 + l) * 4) = c11;
            __syncthreads();
            if (owner && (w & 1) == 1) {
                #pragma unroll
                for (int v = 0; v < 8; ++v)
                    r += *(const floatx4*)(rsc + (size_t)((v * 2 + bt_o) * 64 + l) * 4);
            }

            if (owner) {
                char* hw = hp + (size_t)((t + 1) & 1) * (NBNR * 2);
                #pragma unroll
                for (int j = 0; j < 4; ++j) {
                    float hn = (1.0f - LEAK) * hs[j] + LEAK * tanhf(r[j] + bias);
                    hs[j] = hn;
                    const int bj = bhalf * 32 + bt_o * 16 + g * 4 + j;
                    size_t byte = (size_t)((bj >> 4) * 64 + cu) * 1024
                                + (size_t)((gg * 16 + (bj & 15)) * 8 + ee) * 2;
                    stH((_Float16*)(hw + byte), (_Float16)hn);
                    if (ROLE == 1)
                        __builtin_nontemporal_store(hn, out + (size_t)t * NBNR + (size_t)bj * NR + ncol);
                    if (t == S_LEN - 1)
                        __builtin_nontemporal_store(hn, hn_base + (size_t)bj * NR + ncol);
                }
            }
        }
        if (s < S_LEN) gbar(bar);
    }
}

// 256 blocks: role = bid>>7; within role: fgrp = (bid&127)>>1, bhalf = bid&1
__global__ void __launch_bounds__(TPB, 1) esn_kernel(
    const float* __restrict__ b0v, const float* __restrict__ b1v,
    const float* Whh0, const float* Win0,
    const float* Whh1, const float* Win1,
    const char* __restrict__ xe,
    char* h0p, char* h1p,
    unsigned* __restrict__ bar, float* __restrict__ out)
{
    __shared__ __align__(16) char wlds[128 * 1024];    // fg1 weights, fragment order
    __shared__ __align__(16) float rsc[16 * 64 * 4];   // 16 KiB two-phase reduction
    const int bid = blockIdx.x;
    const int sub = bid & 127;
    const int r0 = (sub >> 1) * 32;
    const int bhalf = sub & 1;
    if (bid < 128)
        esn_layer_run<9, NI, 0>(b0v, Whh0, Win0, xe, h0p, nullptr,
                                out, bar, wlds, rsc, r0, bhalf);
    else
        esn_layer_run<16, NR, 1>(b1v, Whh1, Win1, nullptr, h1p, h0p,
                                 out, bar, wlds, rsc, r0, bhalf);
}

extern "C" void kernel_launch(void* const* d_in, const int* in_sizes, int n_in,
                              void* d_out, int out_size, void* d_ws, size_t ws_size,
                              hipStream_t stream) {
    const float* x    = (const float*)d_in[0];
    const float* Win0 = (const float*)d_in[1];
    const float* Whh0 = (const float*)d_in[2];
    const float* b0   = (const float*)d_in[3];
    const float* Win1 = (const float*)d_in[4];
    const float* Whh1 = (const float*)d_in[5];
    const float* b1   = (const float*)d_in[6];

    char* ws = (char*)d_ws;
    char* xe  = ws + OFF_XE;
    char* h0p = ws + OFF_H0;
    char* h1p = ws + OFF_H1;
    unsigned* bar = (unsigned*)(ws + OFF_BAR);
    float* out = (float*)d_out;

    // zero barrier + both fragment-order h exchanges (initial state h=0)
    (void)hipMemsetAsync(ws, 0, OFF_XE, stream);

    xprep_kernel<<<dim3(S_LEN), dim3(512), 0, stream>>>(x, (_Float16*)xe);

    void* args[] = { (void*)&b0, (void*)&b1, (void*)&Whh0, (void*)&Win0,
                     (void*)&Whh1, (void*)&Win1, (void*)&xe, (void*)&h0p,
                     (void*)&h1p, (void*)&bar, (void*)&out };
    hipError_t e = hipLaunchCooperativeKernel((void*)esn_kernel, dim3(NBLK), dim3(TPB),
                                              args, 0, stream);
    if (e != hipSuccess) {
        esn_kernel<<<dim3(NBLK), dim3(TPB), 0, stream>>>(
            b0, b1, Whh0, Win0, Whh1, Win1, xe, h0p, h1p, bar, out);
    }
}

// Round 10
// 9592.690 us; speedup vs baseline: 1.1344x; 1.1344x over previous
//
#include <hip/hip_runtime.h>

typedef _Float16 half8 __attribute__((ext_vector_type(8)));
typedef float floatx4 __attribute__((ext_vector_type(4)));

#define S_LEN 512
#define NB 64
#define NI 256
#define NR 2048
#define LEAK 0.9f

#define NBLK 128
#define TPB 512
#define LBLK 64
#define NBNR ((size_t)NB * NR)

#define CHT0 72      /* concat K chunks layer0: 64 recurrent + 8 input */
#define CHT1 128     /* layer1: 64 recurrent + 64 y0 */

// ---- workspace offsets ----
#define OFF_BAR ((size_t)0)
#define OFF_H0  ((size_t)4096)
#define OFF_H1  (OFF_H0 + 2 * NBNR * 2)
#define OFF_XE  (OFF_H1 + 2 * NBNR * 2)
#define SZ_XE   ((size_t)S_LEN * NB * NI * 2)
#define OFF_W0  (OFF_XE + SZ_XE)
#define SZ_W0   ((size_t)128 * CHT0 * 1024)
#define OFF_W1  (OFF_W0 + SZ_W0)
#define SZ_W1   ((size_t)128 * CHT1 * 1024)
#define WS_NEED (OFF_W1 + SZ_W1)

__device__ __forceinline__ half8 cvt8(const float* s) {
    float4 p = *(const float4*)s, q = *(const float4*)(s + 4);
    half8 v;
    v[0] = (_Float16)p.x; v[1] = (_Float16)p.y; v[2] = (_Float16)p.z; v[3] = (_Float16)p.w;
    v[4] = (_Float16)q.x; v[5] = (_Float16)q.y; v[6] = (_Float16)q.z; v[7] = (_Float16)q.w;
    return v;
}

// x fp32 -> fp16 in fragment order (R5-proven layout)
__global__ void xprep_kernel(const float* __restrict__ x, _Float16* __restrict__ xe) {
    const int t = blockIdx.x;
    #pragma unroll
    for (int it = 0; it < 4; ++it) {
        const int u = it * 8 + (threadIdx.x >> 6);
        const int l = threadIdx.x & 63;
        const int b = (u >> 3) * 16 + (l & 15);
        const int i0 = (u & 7) * 32 + (l >> 4) * 8;
        half8 v = cvt8(x + ((size_t)t * NB + b) * NI + i0);
        *(half8*)(xe + (size_t)t * NB * NI + (size_t)u * 512 + (size_t)l * 8) = v;
    }
}

// W fp32 -> fp16 fragment-order units: unit = fg*CHT + ch (1KB), lane l holds
// W[fg*16 + (l&15)][ch*32 + (l>>4)*8 .. +8] as half8 at byte l*16.
__global__ void wprep_kernel(const float* __restrict__ Whh0, const float* __restrict__ Win0,
                             const float* __restrict__ Whh1, const float* __restrict__ Win1,
                             _Float16* __restrict__ w0f, _Float16* __restrict__ w1f) {
    int unit = blockIdx.x * 4 + (threadIdx.x >> 6);
    const int l = threadIdx.x & 63;
    const float* Whh; const float* Win; _Float16* dst; int CHT, KU;
    if (unit < 128 * CHT0) { Whh = Whh0; Win = Win0; dst = w0f; CHT = CHT0; KU = NI; }
    else { unit -= 128 * CHT0; Whh = Whh1; Win = Win1; dst = w1f; CHT = CHT1; KU = NR; }
    const int fg = unit / CHT, ch = unit - fg * CHT;
    const int feat = fg * 16 + (l & 15);
    const int k = ch * 32 + (l >> 4) * 8;
    const float* src = (k < NR) ? Whh + (size_t)feat * NR + k
                                : Win + (size_t)feat * KU + (k - NR);
    *(half8*)(dst + ((size_t)unit << 9) + (size_t)l * 8) = cvt8(src);
}

// two-level grid barrier (R5-proven, verbatim)
__device__ __forceinline__ void gbar(unsigned* bar) {
    __syncthreads();
    if (threadIdx.x == 0) {
        __threadfence();
        unsigned* cnt  = bar + (blockIdx.x & 7) * 32;
        unsigned* root = bar + 256;
        unsigned* gen  = bar + 272;
        unsigned g = __hip_atomic_load(gen, __ATOMIC_RELAXED, __HIP_MEMORY_SCOPE_AGENT);
        bool last = false;
        if (__hip_atomic_fetch_add(cnt, 1u, __ATOMIC_ACQ_REL, __HIP_MEMORY_SCOPE_AGENT) == (NBLK / 8 - 1)) {
            __hip_atomic_store(cnt, 0u, __ATOMIC_RELAXED, __HIP_MEMORY_SCOPE_AGENT);
            if (__hip_atomic_fetch_add(root, 1u, __ATOMIC_ACQ_REL, __HIP_MEMORY_SCOPE_AGENT) == 7u) {
                __hip_atomic_store(root, 0u, __ATOMIC_RELAXED, __HIP_MEMORY_SCOPE_AGENT);
                __hip_atomic_store(gen, g + 1u, __ATOMIC_RELEASE, __HIP_MEMORY_SCOPE_AGENT);
                last = true;
            }
        }
        if (!last)
            while (__hip_atomic_load(gen, __ATOMIC_RELAXED, __HIP_MEMORY_SCOPE_AGENT) == g)
                __builtin_amdgcn_s_sleep(1);
        __threadfence();
    }
    __syncthreads();
}

__device__ __forceinline__ void stage8(half8* d, const char* src, int unitbase, int l) {
    #pragma unroll
    for (int jj = 0; jj < 8; ++jj)
        d[jj] = *(const half8*)(src + ((size_t)(unitbase + jj) << 10) + (size_t)l * 16);
}

// One layer, persistent. 64 blocks/layer x 32 feats; 8 waves = K-slices of the
// 2048-wide recurrent part (8 chunks each) + input part. A ping-pong pipelined.
template <int ROLE, bool WF16>
__device__ __forceinline__ void esn_layer_run(
    const float* __restrict__ bias_v,
    const float* Whh, const float* Win,
    const _Float16* __restrict__ wf,   // fp16 fragment W (WF16 path)
    const char* __restrict__ xe,
    char* hp, const char* h0p,
    float* __restrict__ out,
    unsigned* __restrict__ bar,
    float* __restrict__ rsc, int r0)
{
    const int tid = threadIdx.x;
    const int l = tid & 63, w = tid >> 6, l15 = l & 15, g = l >> 4;
    constexpr int CHT = ROLE ? CHT1 : CHT0;
    const int fg0 = r0 >> 4;

    const int fg_o = w & 1, bt_o = w >> 1;
    const int ncol = r0 + fg_o * 16 + l15;
    const int bj0 = bt_o * 16 + g * 4;
    const float bias = bias_v[ncol];
    const int cu = ncol >> 5, gg = (ncol >> 3) & 3, ee = ncol & 7;
    float hs[4] = {0.f, 0.f, 0.f, 0.f};
    float* hn_base = out + (size_t)S_LEN * NBNR + (size_t)ROLE * NBNR;

    for (int s = 0; s < S_LEN + 1; ++s) {
        const int t = (ROLE == 0) ? s : s - 1;
        const bool active = (ROLE == 0) ? (s < S_LEN) : (s >= 1);
        if (active) {
            const char* hu = hp + (size_t)(t & 1) * (NBNR * 2);
            const char* uu = (ROLE == 0) ? xe + (size_t)t * NB * NI * 2
                                         : h0p + (size_t)((t + 1) & 1) * (NBNR * 2);

            floatx4 acc[2][4];
            #pragma unroll
            for (int fg = 0; fg < 2; ++fg)
                #pragma unroll
                for (int bt = 0; bt < 4; ++bt)
                    acc[fg][bt] = (floatx4){0.f, 0.f, 0.f, 0.f};

            half8 wA[8], wB[8], ab[2][8];

            // ---------- pass 0: recurrent part (chunks w*8 .. w*8+7) ----------
            if (WF16) {
                const _Float16* p0 = wf + (((size_t)fg0 * CHT + w * 8) << 9) + (size_t)l * 8;
                const _Float16* p1 = wf + (((size_t)(fg0 + 1) * CHT + w * 8) << 9) + (size_t)l * 8;
                #pragma unroll
                for (int jj = 0; jj < 8; ++jj) {
                    wA[jj] = *(const half8*)(p0 + ((size_t)jj << 9));
                    wB[jj] = *(const half8*)(p1 + ((size_t)jj << 9));
                }
            } else {
                #pragma unroll
                for (int jj = 0; jj < 8; ++jj) {
                    wA[jj] = cvt8(Whh + (size_t)(r0 + l15) * NR + (w * 8 + jj) * 32 + g * 8);
                    wB[jj] = cvt8(Whh + (size_t)(r0 + 16 + l15) * NR + (w * 8 + jj) * 32 + g * 8);
                }
            }
            stage8(ab[0], hu, w * 8, l);
            #pragma unroll
            for (int bt = 0; bt < 4; ++bt) {
                if (bt < 3) stage8(ab[(bt + 1) & 1], hu, (bt + 1) * 64 + w * 8, l);
                #pragma unroll
                for (int jj = 0; jj < 8; ++jj) {
                    acc[0][bt] = __builtin_amdgcn_mfma_f32_16x16x32_f16(ab[bt & 1][jj], wA[jj], acc[0][bt], 0, 0, 0);
                    acc[1][bt] = __builtin_amdgcn_mfma_f32_16x16x32_f16(ab[bt & 1][jj], wB[jj], acc[1][bt], 0, 0, 0);
                }
            }

            // ---------- pass 1: input part ----------
            if (ROLE == 1) {
                if (WF16) {
                    const _Float16* p0 = wf + (((size_t)fg0 * CHT + 64 + w * 8) << 9) + (size_t)l * 8;
                    const _Float16* p1 = wf + (((size_t)(fg0 + 1) * CHT + 64 + w * 8) << 9) + (size_t)l * 8;
                    #pragma unroll
                    for (int jj = 0; jj < 8; ++jj) {
                        wA[jj] = *(const half8*)(p0 + ((size_t)jj << 9));
                        wB[jj] = *(const half8*)(p1 + ((size_t)jj << 9));
                    }
                } else {
                    #pragma unroll
                    for (int jj = 0; jj < 8; ++jj) {
                        wA[jj] = cvt8(Win + (size_t)(r0 + l15) * NR + (w * 8 + jj) * 32 + g * 8);
                        wB[jj] = cvt8(Win + (size_t)(r0 + 16 + l15) * NR + (w * 8 + jj) * 32 + g * 8);
                    }
                }
                stage8(ab[0], uu, w * 8, l);
                #pragma unroll
                for (int bt = 0; bt < 4; ++bt) {
                    if (bt < 3) stage8(ab[(bt + 1) & 1], uu, (bt + 1) * 64 + w * 8, l);
                    #pragma unroll
                    for (int jj = 0; jj < 8; ++jj) {
                        acc[0][bt] = __builtin_amdgcn_mfma_f32_16x16x32_f16(ab[bt & 1][jj], wA[jj], acc[0][bt], 0, 0, 0);
                        acc[1][bt] = __builtin_amdgcn_mfma_f32_16x16x32_f16(ab[bt & 1][jj], wB[jj], acc[1][bt], 0, 0, 0);
                    }
                }
            } else {
                half8 wiA, wiB, ai[4];
                if (WF16) {
                    wiA = *(const half8*)(wf + (((size_t)fg0 * CHT + 64 + w) << 9) + (size_t)l * 8);
                    wiB = *(const half8*)(wf + (((size_t)(fg0 + 1) * CHT + 64 + w) << 9) + (size_t)l * 8);
                } else {
                    wiA = cvt8(Win + (size_t)(r0 + l15) * NI + w * 32 + g * 8);
                    wiB = cvt8(Win + (size_t)(r0 + 16 + l15) * NI + w * 32 + g * 8);
                }
                #pragma unroll
                for (int bt = 0; bt < 4; ++bt)
                    ai[bt] = *(const half8*)(uu + ((size_t)(bt * 8 + w) << 10) + (size_t)l * 16);
                #pragma unroll
                for (int bt = 0; bt < 4; ++bt) {
                    acc[0][bt] = __builtin_amdgcn_mfma_f32_16x16x32_f16(ai[bt], wiA, acc[0][bt], 0, 0, 0);
                    acc[1][bt] = __builtin_amdgcn_mfma_f32_16x16x32_f16(ai[bt], wiB, acc[1][bt], 0, 0, 0);
                }
            }

            // cross-wave K reduction (R5-proven)
            #pragma unroll
            for (int fg = 0; fg < 2; ++fg)
                #pragma unroll
                for (int bt = 0; bt < 4; ++bt)
                    *(floatx4*)(rsc + (size_t)((w * 8 + fg * 4 + bt) * 64 + l) * 4) = acc[fg][bt];
            __syncthreads();

            floatx4 r = {0.f, 0.f, 0.f, 0.f};
            #pragma unroll
            for (int v = 0; v < 8; ++v)
                r += *(const floatx4*)(rsc + (size_t)((v * 8 + fg_o * 4 + bt_o) * 64 + l) * 4);

            char* hw = hp + (size_t)((t + 1) & 1) * (NBNR * 2);
            #pragma unroll
            for (int j = 0; j < 4; ++j) {
                float hn = (1.0f - LEAK) * hs[j] + LEAK * tanhf(r[j] + bias);
                hs[j] = hn;
                const int bj = bj0 + j;
                size_t byte = (size_t)((bj >> 4) * 64 + cu) * 1024
                            + (size_t)((gg * 16 + (bj & 15)) * 8 + ee) * 2;
                *(_Float16*)(hw + byte) = (_Float16)hn;
                if (ROLE == 1)
                    __builtin_nontemporal_store(hn, out + (size_t)t * NBNR + (size_t)bj * NR + ncol);
                if (t == S_LEN - 1)
                    __builtin_nontemporal_store(hn, hn_base + (size_t)bj * NR + ncol);
            }
        }
        if (s < S_LEN) gbar(bar);
    }
}

template <bool WF16>
__global__ void __launch_bounds__(TPB, 1) esn_kernel(
    const float* __restrict__ b0v, const float* __restrict__ b1v,
    const float* Whh0, const float* Win0,
    const float* Whh1, const float* Win1,
    const _Float16* __restrict__ w0f, const _Float16* __restrict__ w1f,
    const char* __restrict__ xe,
    char* h0p, char* h1p,
    unsigned* __restrict__ bar, float* __restrict__ out)
{
    __shared__ __align__(16) float rsc[64 * 64 * 4];   // 64 KiB reduction scratch
    const int bid = blockIdx.x;
    if (bid < LBLK)
        esn_layer_run<0, WF16>(b0v, Whh0, Win0, w0f, xe, h0p, nullptr,
                               out, bar, rsc, bid * 32);
    else
        esn_layer_run<1, WF16>(b1v, Whh1, Win1, w1f, nullptr, h1p, h0p,
                               out, bar, rsc, (bid - LBLK) * 32);
}

extern "C" void kernel_launch(void* const* d_in, const int* in_sizes, int n_in,
                              void* d_out, int out_size, void* d_ws, size_t ws_size,
                              hipStream_t stream) {
    const float* x    = (const float*)d_in[0];
    const float* Win0 = (const float*)d_in[1];
    const float* Whh0 = (const float*)d_in[2];
    const float* b0   = (const float*)d_in[3];
    const float* Win1 = (const float*)d_in[4];
    const float* Whh1 = (const float*)d_in[5];
    const float* b1   = (const float*)d_in[6];

    char* ws = (char*)d_ws;
    char* xe  = ws + OFF_XE;
    char* h0p = ws + OFF_H0;
    char* h1p = ws + OFF_H1;
    unsigned* bar = (unsigned*)(ws + OFF_BAR);
    _Float16* w0f = (_Float16*)(ws + OFF_W0);
    _Float16* w1f = (_Float16*)(ws + OFF_W1);
    float* out = (float*)d_out;

    const bool wf16 = (ws_size >= WS_NEED);

    (void)hipMemsetAsync(ws, 0, OFF_XE, stream);
    xprep_kernel<<<dim3(S_LEN), dim3(512), 0, stream>>>(x, (_Float16*)xe);
    if (wf16)
        wprep_kernel<<<dim3((128 * (CHT0 + CHT1)) / 4), dim3(256), 0, stream>>>(
            Whh0, Win0, Whh1, Win1, w0f, w1f);

    void* args[] = { (void*)&b0, (void*)&b1, (void*)&Whh0, (void*)&Win0,
                     (void*)&Whh1, (void*)&Win1, (void*)&w0f, (void*)&w1f,
                     (void*)&xe, (void*)&h0p, (void*)&h1p, (void*)&bar, (void*)&out };
    void* fn = wf16 ? (void*)esn_kernel<true> : (void*)esn_kernel<false>;
    hipError_t e = hipLaunchCooperativeKernel(fn, dim3(NBLK), dim3(TPB),
                                              args, 0, stream);
    if (e != hipSuccess) {
        if (wf16)
            esn_kernel<true><<<dim3(NBLK), dim3(TPB), 0, stream>>>(
                b0, b1, Whh0, Win0, Whh1, Win1, w0f, w1f, xe, h0p, h1p, bar, out);
        else
            esn_kernel<false><<<dim3(NBLK), dim3(TPB), 0, stream>>>(
                b0, b1, Whh0, Win0, Whh1, Win1, w0f, w1f, xe, h0p, h1p, bar, out);
    }
}